// Round 6
// baseline (19090.277 us; speedup 1.0000x reference)
//
#include <hip/hip_runtime.h>

// CT-LSTM (neural Hawkes) on MI355X. B=32, T=512, H=1024.
// PRIMARY: one persistent kernel (plain launch, 256 WGs x 256 thr, 1 WG/CU via
//   87.6KB dynamic LDS). rec_W recurrent half resident in VGPRs (112/lane).
//   One flag-barrier per step (self-resetting, monotonic across graph replays,
//   bounded spin -> can't wedge the container).
// FALLBACK (launch error only): proven multi-launch design (8.04 ms, r2).

#define H   1024
#define B   32
#define T   512
#define NG  7
#define C7  7168
#define K2  2048
#define NWG 256

typedef __attribute__((ext_vector_type(4))) float f32x4;

// ---------------- static device scratch ----------------
__device__ __attribute__((aligned(16))) float g_Wt[(size_t)C7 * K2];   // fallback
__device__ __attribute__((aligned(16))) float g_w1t[(size_t)H * H];    // fallback
__device__ __attribute__((aligned(16))) float g_w2t[(size_t)H * H];    // fallback
__device__ __attribute__((aligned(16))) float g_embp[(size_t)33 * C7]; // fallback
__device__ __attribute__((aligned(16))) float g_hbuf[2][B * H];        // both paths
__device__ __attribute__((aligned(16))) float g_cd[B * H];             // fallback
__device__ __attribute__((aligned(16))) float g_cb[B * H];             // fallback
__device__ unsigned g_flags[NWG];  // barrier flags; zero at load; monotonic forever

// ---------------- fast transcendentals (proven r2, absmax 1.5e-5) ----------------
__device__ __forceinline__ float sig_f(float x){
  return __builtin_amdgcn_rcpf(1.f + __builtin_amdgcn_exp2f(-1.44269504089f * x));
}
__device__ __forceinline__ float tanh_f(float x){
  float t = __builtin_amdgcn_exp2f(2.88539008178f * x);
  return 1.f - 2.f * __builtin_amdgcn_rcpf(t + 1.f);
}
__device__ __forceinline__ float softplus_f(float x){
  float p = __builtin_amdgcn_exp2f(-1.44269504089f * fabsf(x));
  return fmaxf(x, 0.f) + 0.69314718056f * __builtin_amdgcn_logf(1.f + p);
}

// ---------------- DPP 16-lane-row sum (VALU pipe) ----------------
template<int C>
__device__ __forceinline__ float dppadd(float a){
  int t = __builtin_amdgcn_mov_dpp(__float_as_int(a), C, 0xF, 0xF, true);
  return a + __int_as_float(t);
}
__device__ __forceinline__ float row16_sum(float a){
  a = dppadd<0xB1>(a);   // quad_perm xor1
  a = dppadd<0x4E>(a);   // quad_perm xor2
  a = dppadd<0x141>(a);  // row_half_mirror
  a = dppadd<0x140>(a);  // row_mirror
  return a;
}

__device__ __forceinline__ float d4(f32x4 a, f32x4 b, float s){
  s = __builtin_fmaf(a.x, b.x, s); s = __builtin_fmaf(a.y, b.y, s);
  s = __builtin_fmaf(a.z, b.z, s); s = __builtin_fmaf(a.w, b.w, s);
  return s;
}

__device__ __forceinline__ void loadrow(const float* src, int ln, f32x4 hv[4]){
  const f32x4* p = (const f32x4*)src;
  #pragma unroll
  for (int i = 0; i < 4; ++i) hv[i] = p[i * 64 + ln];   // 16B/lane coalesced
}

// fallback path: weight slice from transposed g_Wt
__device__ __forceinline__ void load_wslice(const float* Wbase, int colb, int ln,
                                            int kofs, f32x4 w[NG][4]){
  #pragma unroll
  for (int g = 0; g < NG; ++g){
    const float* cp = Wbase + (size_t)(g * H + colb) * K2 + kofs;
    #pragma unroll
    for (int i = 0; i < 4; ++i) w[g][i] = *(const f32x4*)(cp + (i * 64 + ln) * 4);
  }
}

// persistent path: gather slice directly from UNtransposed rec_W (one-time)
__device__ __forceinline__ void load_w_direct(const float* recW, int colb, int ln,
                                              int kofs, f32x4 w[NG][4]){
  #pragma unroll
  for (int g = 0; g < NG; ++g)
    #pragma unroll
    for (int i = 0; i < 4; ++i){
      const float* base = recW + (size_t)(kofs + i * 256 + ln * 4) * C7 + g * H + colb;
      w[g][i].x = base[0];
      w[g][i].y = base[C7];
      w[g][i].z = base[2 * C7];
      w[g][i].w = base[3 * C7];
    }
}

// one b-row: 7 gate partials -> 4 sixteen-lane partials each into gp
__device__ __forceinline__ void row_partial(const f32x4 hv[4], const f32x4 w[NG][4],
                                            float* gp, int bi, int wv, int ln){
  float a[NG];
  #pragma unroll
  for (int g = 0; g < NG; ++g){
    float s = 0.f;
    #pragma unroll
    for (int i = 0; i < 4; ++i) s = d4(hv[i], w[g][i], s);
    a[g] = row16_sum(s);
  }
  int m = ln & 15;
  float v = a[0];
  v = (m==1)?a[1]:v; v = (m==2)?a[2]:v; v = (m==3)?a[3]:v;
  v = (m==4)?a[4]:v; v = (m==5)?a[5]:v; v = (m==6)?a[6]:v;
  if (m < NG) gp[bi * 112 + wv * 28 + m * 4 + (ln >> 4)] = v;
}

// NR rows from global src, pipelined one row ahead (proven r2)
template<int NR>
__device__ __forceinline__ void mm_block(const float* src, const f32x4 w[NG][4],
                                         float* gp, int wv, int ln){
  f32x4 ha[4], hb[4];
  loadrow(src, ln, ha);
  #pragma unroll
  for (int b = 0; b < NR; b += 2){
    if (b + 1 < NR) loadrow(src + (b + 1) * H, ln, hb);
    row_partial(ha, w, gp, b, wv, ln);
    if (b + 2 < NR) loadrow(src + (b + 2) * H, ln, ha);
    if (b + 1 < NR) row_partial(hb, w, gp, b + 1, wv, ln);
  }
}

// ---------------- grid flag-barrier (no cooperative API) ----------------
// target is monotonically increasing; flags never reset (wrap-safe compare).
// Bounded spin: a visibility bug -> wrong answer + finite runtime, NOT a hang.
__device__ __forceinline__ void flag_barrier(unsigned target, int tid, int bid){
  __syncthreads();                      // all LDS/global work in this WG done
  if (tid == 0){
    __threadfence();                    // agent release: waitcnt + L2 writeback
    __hip_atomic_store(&g_flags[bid], target, __ATOMIC_RELAXED,
                       __HIP_MEMORY_SCOPE_AGENT);
  }
  // distributed poll: thread tid watches flags[tid] (NWG == block size == 256)
  for (int spin = 0; spin < 32768; ++spin){
    unsigned v = __hip_atomic_load(&g_flags[tid], __ATOMIC_RELAXED,
                                   __HIP_MEMORY_SCOPE_AGENT);
    if ((int)(v - target) >= 0) break;
    __builtin_amdgcn_s_sleep(1);
  }
  __threadfence();                      // agent acquire: invalidate stale lines
  __syncthreads();
}

// =====================================================================
// ==================  PERSISTENT KERNEL (plain launch)  ===============
// =====================================================================
// LDS layout (float indices), dynamic:
#define P_TM   0                    // tm cache [32][520]
#define TMS    520
#define P_EMBP (32*TMS)             // 16640 : [33][28]  e*28 + g*4 + hl
#define P_GP   (P_EMBP + 33*28)     // 17564 : [33][112] partials
#define P_CC   (P_GP + 33*112)      // 21260 : state c   [B*4]
#define P_CB   (P_CC + 128)
#define P_OO   (P_CB + 128)
#define P_DD   (P_OO + 128)
#define P_CDL  (P_DD + 128)
#define DYN_LDS_BYTES (21904 * 4)   // 87616 B > 80KiB -> exactly 1 WG/CU

extern "C" __global__ void __launch_bounds__(256, 1)
ctlstm_persist(const int* __restrict__ ev, const float* __restrict__ tm,
               const float* __restrict__ recW, const float* __restrict__ recb,
               const float* __restrict__ emb,  const float* __restrict__ w1W,
               const float* __restrict__ w1b,  const float* __restrict__ w2W,
               const float* __restrict__ w2b,  float* __restrict__ out)
{
  extern __shared__ float lds[];
  const int tid = threadIdx.x, wg = blockIdx.x;
  const int wv = tid >> 6, ln = tid & 63;
  const int colb = wg * 4 + wv;

  // barrier base: all flags ended equal last run (or 0 at module load)
  const unsigned base = __hip_atomic_load(&g_flags[tid], __ATOMIC_RELAXED,
                                          __HIP_MEMORY_SCOPE_AGENT);
  unsigned bk = 0;                       // barrier sequence number

  // ---- preload tm into LDS (once) ----
  for (int i = tid; i < B * T; i += 256){
    int b = i >> 9, t = i & 511;
    lds[P_TM + b * TMS + t] = tm[i];
  }

  f32x4 w[NG][4];

  // ---- emb_proj: feed-half weights x 33 embedding rows ----
  load_w_direct(recW, colb, ln, 0, w);
  __syncthreads();
  mm_block<33>(emb, w, lds + P_GP, wv, ln);
  __syncthreads();
  for (int idx = tid; idx < 33 * 4; idx += 256){
    int e = idx >> 2, hl = idx & 3, col = wg * 4 + hl;
    #pragma unroll
    for (int g = 0; g < NG; ++g){
      const float* pp = lds + P_GP + e * 112 + hl * 28 + g * 4;
      lds[P_EMBP + e * 28 + g * 4 + hl] =
          recb[g * H + col] + ((pp[0] + pp[1]) + (pp[2] + pp[3]));
    }
  }
  // ---- recurrent-half weights -> registers for the whole scan ----
  load_w_direct(recW, colb, ln, H, w);
  __syncthreads();

  // ---- carry0 = recurrence(emb[0], 0, 0, 0) ----
  if (tid < 128){
    int hl = tid & 3, si = tid;
    float G0 = lds[P_EMBP + 0 * 4 + hl];
    float G2 = lds[P_EMBP + 2 * 4 + hl];
    float G3 = lds[P_EMBP + 3 * 4 + hl];
    float G4 = lds[P_EMBP + 4 * 4 + hl];
    float G6 = lds[P_EMBP + 6 * 4 + hl];
    float gz = tanh_f(G2);
    lds[P_CC + si] = sig_f(G0) * gz;
    lds[P_OO + si] = sig_f(G3);
    lds[P_CB + si] = sig_f(G4) * gz;
    lds[P_DD + si] = softplus_f(G6);
  }
  __syncthreads();

  // ---- sequential scan: one flag-barrier per step ----
  for (int t = 0; t < T; ++t){
    if (tid < 128){                      // decay -> h_d(t) -> global dbuf
      int b = tid >> 2, hl = tid & 3, si = tid;
      float dur = lds[P_TM + b * TMS + t];
      float c  = lds[P_CC + si], cb = lds[P_CB + si];
      float oo = lds[P_OO + si], dd = lds[P_DD + si];
      float cd = cb + (c - cb) * __builtin_amdgcn_exp2f(-1.44269504089f * dd * dur);
      lds[P_CDL + si] = cd;
      g_hbuf[t & 1][b * H + wg * 4 + hl] = oo * tanh_f(cd);
    }
    flag_barrier(base + (++bk), tid, wg); // all h_d(t) slices visible everywhere
    if (t == T - 1) break;               // h_last = g_hbuf[1]

    mm_block<B>(g_hbuf[t & 1], w, lds + P_GP, wv, ln);
    __syncthreads();

    if (tid < 128){                      // fold partials + emb_proj[ev_t], update
      int b = tid >> 2, hl = tid & 3, si = tid;
      int e = ev[b * T + t];
      const int eb = P_EMBP + e * 28;
      const int pb = P_GP + b * 112 + hl * 28;
      float G[NG];
      #pragma unroll
      for (int g = 0; g < NG; ++g)
        G[g] = lds[eb + g * 4 + hl]
             + ((lds[pb + g * 4 + 0] + lds[pb + g * 4 + 1])
              + (lds[pb + g * 4 + 2] + lds[pb + g * 4 + 3]));
      float gz  = tanh_f(G[2]);
      float cd  = lds[P_CDL + si];
      float cbo = lds[P_CB + si];
      lds[P_CC + si] = sig_f(G[1]) * cd  + sig_f(G[0]) * gz;
      lds[P_CB + si] = sig_f(G[5]) * cbo + sig_f(G[4]) * gz;
      lds[P_OO + si] = sig_f(G[3]);
      lds[P_DD + si] = softplus_f(G[6]);
    }
    // ordering vs next iteration's P_GP writes: next flag_barrier entry sync
  }

  // ---- MLP head. phase 0: hid = relu(h_last @ w1 + b1) -> g_hbuf[0] ----
  {
    f32x4 wc[4];
    #pragma unroll
    for (int i = 0; i < 4; ++i){
      const float* bp = w1W + (size_t)(i * 256 + ln * 4) * H + colb;
      wc[i].x = bp[0]; wc[i].y = bp[H]; wc[i].z = bp[2*H]; wc[i].w = bp[3*H];
    }
    #pragma unroll 2
    for (int b = 0; b < B; ++b){
      f32x4 hv[4]; loadrow(g_hbuf[1] + b * H, ln, hv);
      float s = 0.f;
      #pragma unroll
      for (int i = 0; i < 4; ++i) s = d4(hv[i], wc[i], s);
      s = row16_sum(s);
      if ((ln & 15) == 0) lds[P_GP + b * 16 + wv * 4 + (ln >> 4)] = s;
    }
    __syncthreads();
    if (tid < 128){
      int b = tid >> 2, hl = tid & 3, col = wg * 4 + hl;
      const float* pp = lds + P_GP + b * 16 + hl * 4;
      float s = ((pp[0] + pp[1]) + (pp[2] + pp[3])) + w1b[col];
      g_hbuf[0][b * H + col] = fmaxf(s, 0.f);
    }
  }
  flag_barrier(base + (++bk), tid, wg);
  // ---- phase 1: out = hid @ w2 + b2 ----
  {
    f32x4 wc[4];
    #pragma unroll
    for (int i = 0; i < 4; ++i){
      const float* bp = w2W + (size_t)(i * 256 + ln * 4) * H + colb;
      wc[i].x = bp[0]; wc[i].y = bp[H]; wc[i].z = bp[2*H]; wc[i].w = bp[3*H];
    }
    #pragma unroll 2
    for (int b = 0; b < B; ++b){
      f32x4 hv[4]; loadrow(g_hbuf[0] + b * H, ln, hv);
      float s = 0.f;
      #pragma unroll
      for (int i = 0; i < 4; ++i) s = d4(hv[i], wc[i], s);
      s = row16_sum(s);
      if ((ln & 15) == 0) lds[P_GP + b * 16 + wv * 4 + (ln >> 4)] = s;
    }
    __syncthreads();
    if (tid < 128){
      int b = tid >> 2, hl = tid & 3, col = wg * 4 + hl;
      const float* pp = lds + P_GP + b * 16 + hl * 4;
      out[b * H + col] = ((pp[0] + pp[1]) + (pp[2] + pp[3])) + w2b[col];
    }
  }
}

// =====================================================================
// ====================  FALLBACK MULTI-LAUNCH PATH  ===================
// =====================================================================

extern "C" __global__ void __launch_bounds__(256)
transpose_k(const float* __restrict__ in, int which, int R, int C){
  __shared__ float tls[64 * 65];
  float* outp = (which == 0) ? g_Wt : (which == 1 ? g_w1t : g_w2t);
  int tx = threadIdx.x & 63, ty = threadIdx.x >> 6;
  size_t c0 = (size_t)blockIdx.x * 64, r0 = (size_t)blockIdx.y * 64;
  #pragma unroll
  for (int i = 0; i < 16; ++i){
    int r = i * 4 + ty;
    tls[r * 65 + tx] = in[(r0 + r) * (size_t)C + c0 + tx];
  }
  __syncthreads();
  #pragma unroll
  for (int i = 0; i < 16; ++i){
    int c = i * 4 + ty;
    outp[(c0 + c) * (size_t)R + r0 + tx] = tls[tx * 65 + c];
  }
}

extern "C" __global__ void __launch_bounds__(256, 1)
embproj_k(const float* __restrict__ emb, const float* __restrict__ recb){
  __shared__ float gp[33 * 112];
  int tid = threadIdx.x, wg = blockIdx.x, wv = tid >> 6, ln = tid & 63;
  int colb = wg * 4 + wv;
  f32x4 w[NG][4];
  load_wslice(g_Wt, colb, ln, 0, w);
  mm_block<33>(emb, w, gp, wv, ln);
  __syncthreads();
  for (int idx = tid; idx < 33 * 4; idx += 256){
    int e = idx >> 2, hl = idx & 3, col = wg * 4 + hl;
    #pragma unroll
    for (int g = 0; g < NG; ++g){
      const float* pp = gp + e * 112 + hl * 28 + g * 4;
      g_embp[(size_t)e * C7 + g * H + col] =
          recb[g * H + col] + ((pp[0] + pp[1]) + (pp[2] + pp[3]));
    }
  }
}

extern "C" __global__ void __launch_bounds__(256)
init_k(const float* __restrict__ tm){
  int tid = threadIdx.x, wg = blockIdx.x;
  if (tid < 128){
    int b = tid >> 2, hl = tid & 3, col = wg * 4 + hl, si = b * H + col;
    float G[NG];
    #pragma unroll
    for (int g = 0; g < NG; ++g) G[g] = g_embp[(size_t)g * H + col];
    float gz = tanh_f(G[2]);
    float c  = sig_f(G[0]) * gz;
    float cb = sig_f(G[4]) * gz;
    float dd = softplus_f(G[6]);
    float dur = tm[b * T];
    float cd = cb + (c - cb) * __builtin_amdgcn_exp2f(-1.44269504089f * dd * dur);
    g_cd[si] = cd; g_cb[si] = cb;
    g_hbuf[0][si] = sig_f(G[3]) * tanh_f(cd);
  }
}

extern "C" __global__ void __launch_bounds__(256, 1)
step_k(int t, const int* __restrict__ ev, const float* __restrict__ tm){
  __shared__ float gp[B * 112];
  int tid = threadIdx.x, wg = blockIdx.x, wv = tid >> 6, ln = tid & 63;
  int colb = wg * 4 + wv;
  f32x4 w[NG][4];
  load_wslice(g_Wt, colb, ln, H, w);
  const float* hprev = g_hbuf[(t - 1) & 1];
  mm_block<B>(hprev, w, gp, wv, ln);
  __syncthreads();
  if (tid < 128){
    int b = tid >> 2, hl = tid & 3, col = wg * 4 + hl, si = b * H + col;
    int e = ev[b * T + t - 1];
    const float* ep = g_embp + (size_t)e * C7 + col;
    float G[NG];
    #pragma unroll
    for (int g = 0; g < NG; ++g){
      const float* pp = gp + b * 112 + hl * 28 + g * 4;
      G[g] = ep[(size_t)g * H] + ((pp[0] + pp[1]) + (pp[2] + pp[3]));
    }
    float gz  = tanh_f(G[2]);
    float cdp = g_cd[si], cbp = g_cb[si];
    float c   = sig_f(G[1]) * cdp + sig_f(G[0]) * gz;
    float cb  = sig_f(G[5]) * cbp + sig_f(G[4]) * gz;
    float dd  = softplus_f(G[6]);
    float dur = tm[b * T + t];
    float cd  = cb + (c - cb) * __builtin_amdgcn_exp2f(-1.44269504089f * dd * dur);
    g_cd[si] = cd; g_cb[si] = cb;
    g_hbuf[t & 1][si] = sig_f(G[3]) * tanh_f(cd);
  }
}

extern "C" __global__ void __launch_bounds__(256, 1)
mlp_k(int phase, const float* __restrict__ bias, float* __restrict__ outp){
  __shared__ float gp[B * 16];
  int tid = threadIdx.x, wg = blockIdx.x, wv = tid >> 6, ln = tid & 63;
  int colb = wg * 4 + wv;
  const float* Wt   = phase ? g_w2t : g_w1t;
  const float* hsrc = phase ? g_hbuf[0] : g_hbuf[1];
  f32x4 w[4];
  #pragma unroll
  for (int i = 0; i < 4; ++i)
    w[i] = *(const f32x4*)(Wt + (size_t)colb * H + (i * 64 + ln) * 4);
  #pragma unroll 2
  for (int b = 0; b < B; ++b){
    f32x4 hv[4]; loadrow(hsrc + b * H, ln, hv);
    float s = 0.f;
    #pragma unroll
    for (int i = 0; i < 4; ++i) s = d4(hv[i], w[i], s);
    s = row16_sum(s);
    if ((ln & 15) == 0) gp[b * 16 + wv * 4 + (ln >> 4)] = s;
  }
  __syncthreads();
  if (tid < 128){
    int b = tid >> 2, hl = tid & 3, col = wg * 4 + hl;
    const float* pp = gp + b * 16 + hl * 4;
    float s = ((pp[0] + pp[1]) + (pp[2] + pp[3])) + bias[col];
    if (!phase) g_hbuf[0][b * H + col] = fmaxf(s, 0.f);
    else        outp[b * H + col] = s;
  }
}

// ---------------- host ----------------
extern "C" void kernel_launch(void* const* d_in, const int* in_sizes, int n_in,
                              void* d_out, int out_size, void* d_ws, size_t ws_size,
                              hipStream_t stream)
{
  const int*   ev = (const int*)  d_in[0];
  const float* tm = (const float*)d_in[1];
  const float* rW = (const float*)d_in[2];
  const float* rb = (const float*)d_in[3];
  const float* em = (const float*)d_in[4];
  const float* w1 = (const float*)d_in[5];
  const float* b1 = (const float*)d_in[6];
  const float* w2 = (const float*)d_in[7];
  const float* b2 = (const float*)d_in[8];
  float* outp = (float*)d_out;
  (void)d_ws; (void)ws_size; (void)in_sizes; (void)n_in; (void)out_size;

  // opt-in to >64KB dynamic LDS (host-side attr, capture-safe: no stream op)
  hipFuncSetAttribute((const void*)ctlstm_persist,
                      hipFuncAttributeMaxDynamicSharedMemorySize, DYN_LDS_BYTES);

  (void)hipGetLastError();  // clear sticky
  hipLaunchKernelGGL(ctlstm_persist, dim3(NWG), dim3(256), DYN_LDS_BYTES, stream,
                     ev, tm, rW, rb, em, w1, b1, w2, b2, outp);
  if (hipGetLastError() == hipSuccess) return;

  // ---------- proven multi-launch fallback (8.04 ms) ----------
  dim3 blk(256);
  hipLaunchKernelGGL(transpose_k, dim3(C7 / 64, K2 / 64), blk, 0, stream, rW, 0, K2, C7);
  hipLaunchKernelGGL(transpose_k, dim3(H / 64, H / 64),  blk, 0, stream, w1, 1, H, H);
  hipLaunchKernelGGL(transpose_k, dim3(H / 64, H / 64),  blk, 0, stream, w2, 2, H, H);
  hipLaunchKernelGGL(embproj_k, dim3(NWG), blk, 0, stream, em, rb);
  hipLaunchKernelGGL(init_k,    dim3(NWG), blk, 0, stream, tm);
  for (int t = 1; t < T; ++t)
    hipLaunchKernelGGL(step_k, dim3(NWG), blk, 0, stream, t, ev, tm);
  hipLaunchKernelGGL(mlp_k, dim3(NWG), blk, 0, stream, 0, b1, outp);
  hipLaunchKernelGGL(mlp_k, dim3(NWG), blk, 0, stream, 1, b2, outp);
}